// Round 1
// baseline (672.315 us; speedup 1.0000x reference)
//
#include <hip/hip_runtime.h>
#include <math.h>

#define HIDDEN 4096
#define NEXP   64
#define NTOK   16384
#define BT     32                 // tokens per block
#define NW     8                  // waves per block = split-K factor (matches old KCHUNKS)
#define KC     (HIDDEN / NW)      // 512 k per wave-chunk

// Fused gating kernel: fp32 GEMM (register-tiled, NO LDS in main loop),
// cross-wave split-K reduction in LDS, softmax + top-2, one launch, no workspace.
//
// Wave layout: lane -> (i = lane&7 token-group of 4, j = lane>>3 expert-group of 8).
// Per lane: 4 tokens x 8 experts accumulators. X rows read direct from global
// (8-lane-duplicated addresses coalesce to one transaction; x is read exactly once
// from HBM). W rows (1 MB total) are L2-resident and read direct from global.
// Per 4-k group: 12 x global_load_dwordx4 vs 128 FMAs -> VALU-bound (~55 us floor).
//
// Numerics: identical FMA chain to the previous passing kernel:
//   per (tok,exp): sequential fmaf over k within each 512-chunk,
//   logits = bias + p0 + p1 + ... + p7 in chunk order, same expf/softmax/shuffles.
__global__ __launch_bounds__(512, 4)
void gating_fused(const float* __restrict__ x, const float* __restrict__ W,
                  const float* __restrict__ bias, float* __restrict__ out) {
    __shared__ float red[NW][BT][NEXP];   // 64 KB: per-chunk partial logits

    const int tid  = threadIdx.x;
    const int lane = tid & 63;
    const int wid  = tid >> 6;            // wave id == k-chunk id (0..7)
    const int t0   = blockIdx.x * BT;

    const int i  = lane & 7;              // token group (4 tokens)
    const int j  = lane >> 3;             // expert group (8 experts)
    const int k0 = wid * KC;

    const float4* xp[4];
    const float4* wp[8];
#pragma unroll
    for (int m = 0; m < 4; ++m)
        xp[m] = (const float4*)&x[(size_t)(t0 + i * 4 + m) * HIDDEN + k0];
#pragma unroll
    for (int e = 0; e < 8; ++e)
        wp[e] = (const float4*)&W[(size_t)(j * 8 + e) * HIDDEN + k0];

    float acc[4][8];
#pragma unroll
    for (int m = 0; m < 4; ++m)
#pragma unroll
        for (int e = 0; e < 8; ++e) acc[m][e] = 0.f;

#pragma unroll 2
    for (int g = 0; g < KC / 4; ++g) {
        float4 xv[4], wv[8];
#pragma unroll
        for (int m = 0; m < 4; ++m) xv[m] = xp[m][g];
#pragma unroll
        for (int e = 0; e < 8; ++e) wv[e] = wp[e][g];
        const float* xf = (const float*)xv;
        const float* wf = (const float*)wv;
#pragma unroll
        for (int dk = 0; dk < 4; ++dk)        // k ascending: g*4 + dk
#pragma unroll
            for (int m = 0; m < 4; ++m)
#pragma unroll
                for (int e = 0; e < 8; ++e)
                    acc[m][e] = fmaf(xf[m * 4 + dk], wf[e * 4 + dk], acc[m][e]);
    }

    // park this wave's partial tile; one barrier total
#pragma unroll
    for (int m = 0; m < 4; ++m)
#pragma unroll
        for (int e = 0; e < 8; ++e)
            red[wid][i * 4 + m][j * 8 + e] = acc[m][e];
    __syncthreads();

    // softmax + top-2: wave wid handles tokens wid*4 .. wid*4+3, lane = expert
#pragma unroll
    for (int q = 0; q < 4; ++q) {
        const int tt = wid * 4 + q;

        float l = bias[lane];
#pragma unroll
        for (int c = 0; c < NW; ++c)          // chunk order 0..7, same as before
            l += red[c][tt][lane];

        // wave max
        float mx = l;
#pragma unroll
        for (int s = 32; s > 0; s >>= 1)
            mx = fmaxf(mx, __shfl_xor(mx, s, 64));

        // softmax denominator (deterministic butterfly)
        float ssum = expf(l - mx);
#pragma unroll
        for (int s = 32; s > 0; s >>= 1)
            ssum += __shfl_xor(ssum, s, 64);

        // top-1: max value, lower index wins ties
        float v1 = l; int i1 = lane;
#pragma unroll
        for (int s = 32; s > 0; s >>= 1) {
            float ov = __shfl_xor(v1, s, 64);
            int   oi = __shfl_xor(i1, s, 64);
            if (ov > v1 || (ov == v1 && oi < i1)) { v1 = ov; i1 = oi; }
        }
        // top-2: exclude i1
        float v2 = (lane == i1) ? -INFINITY : l;
        int   i2 = lane;
#pragma unroll
        for (int s = 32; s > 0; s >>= 1) {
            float ov = __shfl_xor(v2, s, 64);
            int   oi = __shfl_xor(i2, s, 64);
            if (ov > v2 || (ov == v2 && oi < i2)) { v2 = ov; i2 = oi; }
        }

        if (lane == 0) {
            const int t = t0 + tt;
            const float inv = 1.0f / ssum;
            out[(size_t)t * 2 + 0] = inv;                     // exp(v1-mx)=1 since v1==mx
            out[(size_t)t * 2 + 1] = expf(v2 - mx) * inv;
            out[(size_t)2 * NTOK + t * 2 + 0] = (float)i1;    // indices read back as float32
            out[(size_t)2 * NTOK + t * 2 + 1] = (float)i2;
        }
    }
}

extern "C" void kernel_launch(void* const* d_in, const int* in_sizes, int n_in,
                              void* d_out, int out_size, void* d_ws, size_t ws_size,
                              hipStream_t stream) {
    const float* x = (const float*)d_in[0];
    const float* W = (const float*)d_in[1];
    const float* b = (const float*)d_in[2];
    float* out = (float*)d_out;
    (void)d_ws; (void)ws_size;   // no workspace: no partials round-trip, no second launch

    gating_fused<<<dim3(NTOK / BT), 512, 0, stream>>>(x, W, b, out);
}